// Round 15
// baseline (164.990 us; speedup 1.0000x reference)
//
#include <hip/hip_runtime.h>

#define NN 50000
#define NE 600000
#define DI 128
#define DH 16
#define DC 8
#define RNG 391      // nodes per range (128 ranges x 391 = 50048 >= NN)
#define HCAP 32      // ELL slots per half; half-deg ~ Poisson(6), P(>32) ~ 1e-16
#define ECH (NE / 2) // edges per chunk

typedef unsigned short u16;

// ---------------- K0: xl = x @ W1l, xr = x @ W1r ----------------
__global__ __launch_bounds__(256) void k_gemm1(
    const float* __restrict__ x,
    const float* __restrict__ W1l,
    const float* __restrict__ W1r,
    float* __restrict__ xl,
    float* __restrict__ xr)
{
    int t = blockIdx.x * 256 + threadIdx.x;

    __shared__ float Wc[DI][32];   // [k][j]: j<16 -> W1l, j>=16 -> W1r
    for (int i = threadIdx.x; i < DI * DH; i += 256) {
        int k = i >> 4, j = i & 15;
        Wc[k][j]      = W1l[i];
        Wc[k][j + 16] = W1r[i];
    }
    __syncthreads();
    if (t >= NN * 4) return;
    int n = t >> 2, c = t & 3;
    const int co = c * 8;

    float acc[8];
#pragma unroll
    for (int j = 0; j < 8; ++j) acc[j] = 0.f;

    const float4* xrow = (const float4*)(x + (size_t)n * DI);
#pragma unroll 4
    for (int k4 = 0; k4 < DI / 4; ++k4) {
        float4 xv = xrow[k4];
#pragma unroll
        for (int kk = 0; kk < 4; ++kk) {
            const float* wr = &Wc[k4 * 4 + kk][co];
            float4 w0 = *(const float4*)(wr);
            float4 w1 = *(const float4*)(wr + 4);
            float xs = (&xv.x)[kk];
            acc[0] += xs * w0.x; acc[1] += xs * w0.y;
            acc[2] += xs * w0.z; acc[3] += xs * w0.w;
            acc[4] += xs * w1.x; acc[5] += xs * w1.y;
            acc[6] += xs * w1.z; acc[7] += xs * w1.w;
        }
    }
    float* o = (c < 2) ? (xl + (size_t)n * DH + c * 8)
                       : (xr + (size_t)n * DH + (c - 2) * 8);
    *(float4*)(o)     = make_float4(acc[0], acc[1], acc[2], acc[3]);
    *(float4*)(o + 4) = make_float4(acc[4], acc[5], acc[6], acc[7]);
}

// ---------------- K1: LDS-local ELL build, no global atomics ----------------
// block = (range r, chunk c): scans chunk c's 300K edges, buckets dst in
// [r*RNG,(r+1)*RNG) into LDS, flushes half-rows ell[n][c*32..) coalesced.
__global__ __launch_bounds__(256) void k_build(
    const int* __restrict__ src, const int* __restrict__ dst,
    u16* __restrict__ ell, int* __restrict__ cnt0, int* __restrict__ cnt1)
{
    __shared__ u16 sell[RNG * HCAP];   // ~25KB
    __shared__ int scnt[RNG];
    const int tid = threadIdx.x;
    const int r = blockIdx.x >> 1, c = blockIdx.x & 1;
    const int nbase = r * RNG;
    const int nend  = min(nbase + RNG, NN);
    const int ebase = c * ECH;

    for (int i = tid; i < RNG; i += 256) scnt[i] = 0;
    __syncthreads();

    const int4* d4 = (const int4*)(dst + ebase);
    const int4* s4 = (const int4*)(src + ebase);
    for (int i = tid; i < ECH / 4; i += 256) {
        int4 d = d4[i];
        bool mx = (d.x >= nbase) & (d.x < nend);
        bool my = (d.y >= nbase) & (d.y < nend);
        bool mz = (d.z >= nbase) & (d.z < nend);
        bool mw = (d.w >= nbase) & (d.w < nend);
        if (mx | my | mz | mw) {
            int4 s = s4[i];   // src line loaded only when needed (adjacent 16B)
            if (mx) { int p = atomicAdd(&scnt[d.x - nbase], 1); if (p < HCAP) sell[(d.x - nbase) * HCAP + p] = (u16)s.x; }
            if (my) { int p = atomicAdd(&scnt[d.y - nbase], 1); if (p < HCAP) sell[(d.y - nbase) * HCAP + p] = (u16)s.y; }
            if (mz) { int p = atomicAdd(&scnt[d.z - nbase], 1); if (p < HCAP) sell[(d.z - nbase) * HCAP + p] = (u16)s.z; }
            if (mw) { int p = atomicAdd(&scnt[d.w - nbase], 1); if (p < HCAP) sell[(d.w - nbase) * HCAP + p] = (u16)s.w; }
        }
    }
    __syncthreads();

    // flush: node's half-row = 32 u16 = 4 x uint4, fully coalesced
    for (int i = tid; i < RNG * 4; i += 256) {
        int node = i >> 2, part = i & 3;
        if (nbase + node < NN) {
            uint4 v = ((const uint4*)sell)[i];
            *((uint4*)(ell + (size_t)(nbase + node) * 64 + c * HCAP) + part) = v;
        }
    }
    int* cp = c ? cnt1 : cnt0;
    for (int i = tid; i < RNG; i += 256)
        if (nbase + i < NN) cp[nbase + i] = min(scnt[i], HCAP);
}

// ---------------- K2: agg1 + relu + layer-2 GEMM; 8 threads/node ----------------
// sub = t&7: s = sub>>2 (slot parity), q = sub&3 (feature quad)
__global__ __launch_bounds__(256) void k_l1(
    const int* __restrict__ cnt0, const int* __restrict__ cnt1,
    const u16* __restrict__ ell,
    const float* __restrict__ xl, const float* __restrict__ xr,
    const float* __restrict__ b1,
    const float* __restrict__ W2l, const float* __restrict__ W2r,
    float* __restrict__ zl, float* __restrict__ zr)
{
    int t = blockIdx.x * 256 + threadIdx.x;
    if (t >= NN * 8) return;
    int n = t >> 3, sub = t & 7, s = sub >> 2, q = sub & 3;
    const int q4 = q * 4;

    int len0 = cnt0[n], len1 = cnt1[n];
    const u16* lst = ell + (size_t)n * 64;

    float4 a0 = make_float4(0.f, 0.f, 0.f, 0.f);
#pragma unroll
    for (int h = 0; h < 2; ++h) {
        int lenh = h ? len1 : len0;
        const u16* L = lst + h * HCAP;
        for (int j = 0; j < lenh; j += 8) {
            uint4 w = *(const uint4*)(L + j);
            int i0 = (int)(s ? (w.x >> 16) : (w.x & 0xFFFFu));
            int i1 = (int)(s ? (w.y >> 16) : (w.y & 0xFFFFu));
            int i2 = (int)(s ? (w.z >> 16) : (w.z & 0xFFFFu));
            int i3 = (int)(s ? (w.w >> 16) : (w.w & 0xFFFFu));
            float m0 = (j + 0 + s < lenh) ? 1.f : 0.f;
            float m1 = (j + 2 + s < lenh) ? 1.f : 0.f;
            float m2 = (j + 4 + s < lenh) ? 1.f : 0.f;
            float m3 = (j + 6 + s < lenh) ? 1.f : 0.f;
            i0 = (j + 0 + s < lenh) ? i0 : 0;
            i1 = (j + 2 + s < lenh) ? i1 : 0;
            i2 = (j + 4 + s < lenh) ? i2 : 0;
            i3 = (j + 6 + s < lenh) ? i3 : 0;
            float4 v0 = *(const float4*)(xl + (size_t)i0 * DH + q4);
            float4 v1 = *(const float4*)(xl + (size_t)i1 * DH + q4);
            float4 v2 = *(const float4*)(xl + (size_t)i2 * DH + q4);
            float4 v3 = *(const float4*)(xl + (size_t)i3 * DH + q4);
            a0.x += v0.x*m0 + v1.x*m1 + v2.x*m2 + v3.x*m3;
            a0.y += v0.y*m0 + v1.y*m1 + v2.y*m2 + v3.y*m3;
            a0.z += v0.z*m0 + v1.z*m1 + v2.z*m2 + v3.z*m3;
            a0.w += v0.w*m0 + v1.w*m1 + v2.w*m2 + v3.w*m3;
        }
    }
    a0.x += __shfl_xor(a0.x, 4, 64);
    a0.y += __shfl_xor(a0.y, 4, 64);
    a0.z += __shfl_xor(a0.z, 4, 64);
    a0.w += __shfl_xor(a0.w, 4, 64);

    float inv = 1.0f / fmaxf((float)(len0 + len1), 1.0f);
    float4 r  = *(const float4*)(xr + (size_t)n * DH + q4);
    float4 bb = *(const float4*)(b1 + q4);
    float4 hq;
    hq.x = fmaxf(a0.x * inv + bb.x + r.x, 0.f);
    hq.y = fmaxf(a0.y * inv + bb.y + r.y, 0.f);
    hq.z = fmaxf(a0.z * inv + bb.z + r.z, 0.f);
    hq.w = fmaxf(a0.w * inv + bb.w + r.w, 0.f);

    float4 p1, p2, p3;
    p1.x = __shfl_xor(hq.x, 1, 64); p1.y = __shfl_xor(hq.y, 1, 64);
    p1.z = __shfl_xor(hq.z, 1, 64); p1.w = __shfl_xor(hq.w, 1, 64);
    p2.x = __shfl_xor(hq.x, 2, 64); p2.y = __shfl_xor(hq.y, 2, 64);
    p2.z = __shfl_xor(hq.z, 2, 64); p2.w = __shfl_xor(hq.w, 2, 64);
    p3.x = __shfl_xor(p1.x, 2, 64); p3.y = __shfl_xor(p1.y, 2, 64);
    p3.z = __shfl_xor(p1.z, 2, 64); p3.w = __shfl_xor(p1.w, 2, 64);
    float4 Q[4];
#pragma unroll
    for (int jq = 0; jq < 4; ++jq) {
        int d = jq ^ q;
        Q[jq] = (d == 0) ? hq : (d == 1) ? p1 : (d == 2) ? p2 : p3;
    }

    const float* Wbase = (q < 2) ? (W2l + q * 4) : (W2r + (q - 2) * 4);
    float4 acc = make_float4(0.f, 0.f, 0.f, 0.f);
#pragma unroll
    for (int k = 0; k < DH; ++k) {
        float hk = (k < 4) ? ((const float*)&Q[0])[k & 3]
                 : (k < 8) ? ((const float*)&Q[1])[k & 3]
                 : (k < 12) ? ((const float*)&Q[2])[k & 3]
                 : ((const float*)&Q[3])[k & 3];
        float4 wv = *(const float4*)(Wbase + k * 8);
        acc.x += hk * wv.x; acc.y += hk * wv.y;
        acc.z += hk * wv.z; acc.w += hk * wv.w;
    }
    if (s == 0) {
        float* dstp = (q < 2) ? (zl + (size_t)n * DC + q * 4)
                              : (zr + (size_t)n * DC + (q - 2) * 4);
        *(float4*)dstp = acc;
    }
}

// ---------------- K3: agg2 + b2 + zr -> out; 4 threads/node ----------------
// sub = t&3: s = sub>>1 (slot parity), q = sub&1 (feature quad)
__global__ __launch_bounds__(256) void k_l2(
    const int* __restrict__ cnt0, const int* __restrict__ cnt1,
    const u16* __restrict__ ell,
    const float* __restrict__ zl, const float* __restrict__ zr,
    const float* __restrict__ b2, float* __restrict__ out)
{
    int t = blockIdx.x * 256 + threadIdx.x;
    if (t >= NN * 4) return;
    int n = t >> 2, sub = t & 3, s = sub >> 1, q = sub & 1;
    const int q4 = q * 4;
    int len0 = cnt0[n], len1 = cnt1[n];
    const u16* lst = ell + (size_t)n * 64;

    float4 a0 = make_float4(0.f, 0.f, 0.f, 0.f);
#pragma unroll
    for (int h = 0; h < 2; ++h) {
        int lenh = h ? len1 : len0;
        const u16* L = lst + h * HCAP;
        for (int j = 0; j < lenh; j += 8) {
            uint4 w = *(const uint4*)(L + j);
            int i0 = (int)(s ? (w.x >> 16) : (w.x & 0xFFFFu));
            int i1 = (int)(s ? (w.y >> 16) : (w.y & 0xFFFFu));
            int i2 = (int)(s ? (w.z >> 16) : (w.z & 0xFFFFu));
            int i3 = (int)(s ? (w.w >> 16) : (w.w & 0xFFFFu));
            float m0 = (j + 0 + s < lenh) ? 1.f : 0.f;
            float m1 = (j + 2 + s < lenh) ? 1.f : 0.f;
            float m2 = (j + 4 + s < lenh) ? 1.f : 0.f;
            float m3 = (j + 6 + s < lenh) ? 1.f : 0.f;
            i0 = (j + 0 + s < lenh) ? i0 : 0;
            i1 = (j + 2 + s < lenh) ? i1 : 0;
            i2 = (j + 4 + s < lenh) ? i2 : 0;
            i3 = (j + 6 + s < lenh) ? i3 : 0;
            float4 v0 = *(const float4*)(zl + (size_t)i0 * DC + q4);
            float4 v1 = *(const float4*)(zl + (size_t)i1 * DC + q4);
            float4 v2 = *(const float4*)(zl + (size_t)i2 * DC + q4);
            float4 v3 = *(const float4*)(zl + (size_t)i3 * DC + q4);
            a0.x += v0.x*m0 + v1.x*m1 + v2.x*m2 + v3.x*m3;
            a0.y += v0.y*m0 + v1.y*m1 + v2.y*m2 + v3.y*m3;
            a0.z += v0.z*m0 + v1.z*m1 + v2.z*m2 + v3.z*m3;
            a0.w += v0.w*m0 + v1.w*m1 + v2.w*m2 + v3.w*m3;
        }
    }
    a0.x += __shfl_xor(a0.x, 2, 64);
    a0.y += __shfl_xor(a0.y, 2, 64);
    a0.z += __shfl_xor(a0.z, 2, 64);
    a0.w += __shfl_xor(a0.w, 2, 64);

    if (s == 0) {
        float inv = 1.0f / fmaxf((float)(len0 + len1), 1.0f);
        float4 r  = *(const float4*)(zr + (size_t)n * DC + q4);
        float4 bb = *(const float4*)(b2 + q4);
        float4 o;
        o.x = a0.x * inv + bb.x + r.x;
        o.y = a0.y * inv + bb.y + r.y;
        o.z = a0.z * inv + bb.z + r.z;
        o.w = a0.w * inv + bb.w + r.w;
        *(float4*)(out + (size_t)n * DC + q4) = o;
    }
}

extern "C" void kernel_launch(void* const* d_in, const int* in_sizes, int n_in,
                              void* d_out, int out_size, void* d_ws, size_t ws_size,
                              hipStream_t stream)
{
    const float* x   = (const float*)d_in[0];
    const int*   ei  = (const int*)d_in[1];
    const float* W1l = (const float*)d_in[2];
    const float* b1  = (const float*)d_in[3];
    const float* W1r = (const float*)d_in[4];
    const float* W2l = (const float*)d_in[5];
    const float* b2  = (const float*)d_in[6];
    const float* W2r = (const float*)d_in[7];
    float* out = (float*)d_out;

    const int* src = ei;
    const int* dst = ei + NE;

    // ---- workspace layout (floats first, 16B-aligned) ----
    float* xl  = (float*)d_ws;                      // NN*16
    float* xr  = xl + (size_t)NN * DH;              // NN*16
    float* zl  = xr + (size_t)NN * DH;              // NN*8
    float* zr  = zl + (size_t)NN * DC;              // NN*8
    int* cnt0  = (int*)(zr + (size_t)NN * DC);      // NN
    int* cnt1  = cnt0 + NN;                         // NN
    u16* ell   = (u16*)(cnt1 + NN);                 // NN*64 u16 = 6.4MB
    // total ~16.4 MB

    k_build<<<256, 256, 0, stream>>>(src, dst, ell, cnt0, cnt1);
    k_gemm1<<<(NN * 4 + 255) / 256, 256, 0, stream>>>(x, W1l, W1r, xl, xr);
    k_l1   <<<(NN * 8 + 255) / 256, 256, 0, stream>>>(cnt0, cnt1, ell, xl, xr, b1, W2l, W2r, zl, zr);
    k_l2   <<<(NN * 4 + 255) / 256, 256, 0, stream>>>(cnt0, cnt1, ell, zl, zr, b2, out);
}

// Round 16
// 71.073 us; speedup vs baseline: 2.3214x; 2.3214x over previous
//
#include <hip/hip_runtime.h>

#define NN 50000
#define NE 600000
#define DI 128
#define DH 16
#define DC 8
#define NREP 4     // counter replicas per node (indexed by blockIdx&3)
#define RCAP 16    // slots per replica; per-replica deg ~ Poisson(3), P(>16) ~ 1e-9
#define NBF 2344   // fill blocks: ceil(NE/256)
#define NBG 782    // gemm blocks: ceil(NN*4/256)

typedef unsigned short u16;

// ---------------- K0: zero replicated counters ----------------
__global__ __launch_bounds__(256) void k_zero(int* __restrict__ cnt4)
{
    int t = blockIdx.x * 256 + threadIdx.x;
    if (t < NN) *(int4*)(cnt4 + (size_t)t * 4) = make_int4(0, 0, 0, 0);
}

// ---------------- K1: fill (replica atomics) || gemm1, independent block ranges ----------------
__global__ __launch_bounds__(256) void k_fillgemm(
    const float* __restrict__ x,
    const float* __restrict__ W1l,
    const float* __restrict__ W1r,
    const int* __restrict__ src,
    const int* __restrict__ dst,
    float* __restrict__ xl,
    float* __restrict__ xr,
    int* __restrict__ cnt4,
    u16* __restrict__ ell)
{
    __shared__ float Wc[DI][32];   // gemm blocks only

    if (blockIdx.x < NBF) {
        // ---- fill: 1 edge/thread; replica r = blockIdx&3 cuts per-address RMW concurrency 4x ----
        int e = blockIdx.x * 256 + threadIdx.x;
        if (e >= NE) return;
        int d = dst[e];
        int r = blockIdx.x & (NREP - 1);
        int pos = atomicAdd(&cnt4[(size_t)d * NREP + r], 1);
        if (pos < RCAP) ell[(size_t)d * 64 + r * RCAP + pos] = (u16)src[e];
        return;
    }

    // ---- gemm1: 4 threads/node; thread c computes cols [c*8, c*8+8) ----
    for (int i = threadIdx.x; i < DI * DH; i += 256) {
        int k = i >> 4, j = i & 15;
        Wc[k][j]      = W1l[i];
        Wc[k][j + 16] = W1r[i];
    }
    __syncthreads();

    int t = (blockIdx.x - NBF) * 256 + threadIdx.x;
    if (t >= NN * 4) return;
    int n = t >> 2, c = t & 3;
    const int co = c * 8;

    float acc[8];
#pragma unroll
    for (int j = 0; j < 8; ++j) acc[j] = 0.f;

    const float4* xrow = (const float4*)(x + (size_t)n * DI);
#pragma unroll 4
    for (int k4 = 0; k4 < DI / 4; ++k4) {
        float4 xv = xrow[k4];
#pragma unroll
        for (int kk = 0; kk < 4; ++kk) {
            const float* wr = &Wc[k4 * 4 + kk][co];
            float4 w0 = *(const float4*)(wr);
            float4 w1 = *(const float4*)(wr + 4);
            float xs = (&xv.x)[kk];
            acc[0] += xs * w0.x; acc[1] += xs * w0.y;
            acc[2] += xs * w0.z; acc[3] += xs * w0.w;
            acc[4] += xs * w1.x; acc[5] += xs * w1.y;
            acc[6] += xs * w1.z; acc[7] += xs * w1.w;
        }
    }
    float* o = (c < 2) ? (xl + (size_t)n * DH + c * 8)
                       : (xr + (size_t)n * DH + (c - 2) * 8);
    *(float4*)(o)     = make_float4(acc[0], acc[1], acc[2], acc[3]);
    *(float4*)(o + 4) = make_float4(acc[4], acc[5], acc[6], acc[7]);
}

// ---------------- K2: agg1 + relu + layer-2 GEMM; 8 threads/node ----------------
// sub = t&7: s = sub>>2 (slot parity), q = sub&3 (feature quad)
__global__ __launch_bounds__(256) void k_l1(
    const int* __restrict__ cnt4, const u16* __restrict__ ell,
    const float* __restrict__ xl, const float* __restrict__ xr,
    const float* __restrict__ b1,
    const float* __restrict__ W2l, const float* __restrict__ W2r,
    float* __restrict__ zl, float* __restrict__ zr)
{
    int t = blockIdx.x * 256 + threadIdx.x;
    if (t >= NN * 8) return;
    int n = t >> 3, sub = t & 7, s = sub >> 2, q = sub & 3;
    const int q4 = q * 4;

    int4 c4 = *(const int4*)(cnt4 + (size_t)n * NREP);
    int lens[NREP] = { min(c4.x, RCAP), min(c4.y, RCAP), min(c4.z, RCAP), min(c4.w, RCAP) };
    int len = lens[0] + lens[1] + lens[2] + lens[3];
    const u16* lst = ell + (size_t)n * 64;

    float4 a0 = make_float4(0.f, 0.f, 0.f, 0.f);
#pragma unroll
    for (int h = 0; h < NREP; ++h) {
        int lenh = lens[h];
        const u16* L = lst + h * RCAP;
        for (int j = 0; j < lenh; j += 8) {
            uint4 w = *(const uint4*)(L + j);
            int i0 = (int)(s ? (w.x >> 16) : (w.x & 0xFFFFu));
            int i1 = (int)(s ? (w.y >> 16) : (w.y & 0xFFFFu));
            int i2 = (int)(s ? (w.z >> 16) : (w.z & 0xFFFFu));
            int i3 = (int)(s ? (w.w >> 16) : (w.w & 0xFFFFu));
            float m0 = (j + 0 + s < lenh) ? 1.f : 0.f;
            float m1 = (j + 2 + s < lenh) ? 1.f : 0.f;
            float m2 = (j + 4 + s < lenh) ? 1.f : 0.f;
            float m3 = (j + 6 + s < lenh) ? 1.f : 0.f;
            i0 = (j + 0 + s < lenh) ? i0 : 0;
            i1 = (j + 2 + s < lenh) ? i1 : 0;
            i2 = (j + 4 + s < lenh) ? i2 : 0;
            i3 = (j + 6 + s < lenh) ? i3 : 0;
            float4 v0 = *(const float4*)(xl + (size_t)i0 * DH + q4);
            float4 v1 = *(const float4*)(xl + (size_t)i1 * DH + q4);
            float4 v2 = *(const float4*)(xl + (size_t)i2 * DH + q4);
            float4 v3 = *(const float4*)(xl + (size_t)i3 * DH + q4);
            a0.x += v0.x*m0 + v1.x*m1 + v2.x*m2 + v3.x*m3;
            a0.y += v0.y*m0 + v1.y*m1 + v2.y*m2 + v3.y*m3;
            a0.z += v0.z*m0 + v1.z*m1 + v2.z*m2 + v3.z*m3;
            a0.w += v0.w*m0 + v1.w*m1 + v2.w*m2 + v3.w*m3;
        }
    }
    a0.x += __shfl_xor(a0.x, 4, 64);
    a0.y += __shfl_xor(a0.y, 4, 64);
    a0.z += __shfl_xor(a0.z, 4, 64);
    a0.w += __shfl_xor(a0.w, 4, 64);

    float inv = 1.0f / fmaxf((float)len, 1.0f);
    float4 r  = *(const float4*)(xr + (size_t)n * DH + q4);
    float4 bb = *(const float4*)(b1 + q4);
    float4 hq;
    hq.x = fmaxf(a0.x * inv + bb.x + r.x, 0.f);
    hq.y = fmaxf(a0.y * inv + bb.y + r.y, 0.f);
    hq.z = fmaxf(a0.z * inv + bb.z + r.z, 0.f);
    hq.w = fmaxf(a0.w * inv + bb.w + r.w, 0.f);

    float4 p1, p2, p3;
    p1.x = __shfl_xor(hq.x, 1, 64); p1.y = __shfl_xor(hq.y, 1, 64);
    p1.z = __shfl_xor(hq.z, 1, 64); p1.w = __shfl_xor(hq.w, 1, 64);
    p2.x = __shfl_xor(hq.x, 2, 64); p2.y = __shfl_xor(hq.y, 2, 64);
    p2.z = __shfl_xor(hq.z, 2, 64); p2.w = __shfl_xor(hq.w, 2, 64);
    p3.x = __shfl_xor(p1.x, 2, 64); p3.y = __shfl_xor(p1.y, 2, 64);
    p3.z = __shfl_xor(p1.z, 2, 64); p3.w = __shfl_xor(p1.w, 2, 64);
    float4 Q[4];
#pragma unroll
    for (int jq = 0; jq < 4; ++jq) {
        int d = jq ^ q;
        Q[jq] = (d == 0) ? hq : (d == 1) ? p1 : (d == 2) ? p2 : p3;
    }

    const float* Wbase = (q < 2) ? (W2l + q * 4) : (W2r + (q - 2) * 4);
    float4 acc = make_float4(0.f, 0.f, 0.f, 0.f);
#pragma unroll
    for (int k = 0; k < DH; ++k) {
        float hk = (k < 4) ? ((const float*)&Q[0])[k & 3]
                 : (k < 8) ? ((const float*)&Q[1])[k & 3]
                 : (k < 12) ? ((const float*)&Q[2])[k & 3]
                 : ((const float*)&Q[3])[k & 3];
        float4 wv = *(const float4*)(Wbase + k * 8);
        acc.x += hk * wv.x; acc.y += hk * wv.y;
        acc.z += hk * wv.z; acc.w += hk * wv.w;
    }
    if (s == 0) {
        float* dstp = (q < 2) ? (zl + (size_t)n * DC + q * 4)
                              : (zr + (size_t)n * DC + (q - 2) * 4);
        *(float4*)dstp = acc;
    }
}

// ---------------- K3: agg2 + b2 + zr -> out; 4 threads/node ----------------
// sub = t&3: s = sub>>1 (slot parity), q = sub&1 (feature quad)
__global__ __launch_bounds__(256) void k_l2(
    const int* __restrict__ cnt4, const u16* __restrict__ ell,
    const float* __restrict__ zl, const float* __restrict__ zr,
    const float* __restrict__ b2, float* __restrict__ out)
{
    int t = blockIdx.x * 256 + threadIdx.x;
    if (t >= NN * 4) return;
    int n = t >> 2, sub = t & 3, s = sub >> 1, q = sub & 1;
    const int q4 = q * 4;
    int4 c4 = *(const int4*)(cnt4 + (size_t)n * NREP);
    int lens[NREP] = { min(c4.x, RCAP), min(c4.y, RCAP), min(c4.z, RCAP), min(c4.w, RCAP) };
    int len = lens[0] + lens[1] + lens[2] + lens[3];
    const u16* lst = ell + (size_t)n * 64;

    float4 a0 = make_float4(0.f, 0.f, 0.f, 0.f);
#pragma unroll
    for (int h = 0; h < NREP; ++h) {
        int lenh = lens[h];
        const u16* L = lst + h * RCAP;
        for (int j = 0; j < lenh; j += 8) {
            uint4 w = *(const uint4*)(L + j);
            int i0 = (int)(s ? (w.x >> 16) : (w.x & 0xFFFFu));
            int i1 = (int)(s ? (w.y >> 16) : (w.y & 0xFFFFu));
            int i2 = (int)(s ? (w.z >> 16) : (w.z & 0xFFFFu));
            int i3 = (int)(s ? (w.w >> 16) : (w.w & 0xFFFFu));
            float m0 = (j + 0 + s < lenh) ? 1.f : 0.f;
            float m1 = (j + 2 + s < lenh) ? 1.f : 0.f;
            float m2 = (j + 4 + s < lenh) ? 1.f : 0.f;
            float m3 = (j + 6 + s < lenh) ? 1.f : 0.f;
            i0 = (j + 0 + s < lenh) ? i0 : 0;
            i1 = (j + 2 + s < lenh) ? i1 : 0;
            i2 = (j + 4 + s < lenh) ? i2 : 0;
            i3 = (j + 6 + s < lenh) ? i3 : 0;
            float4 v0 = *(const float4*)(zl + (size_t)i0 * DC + q4);
            float4 v1 = *(const float4*)(zl + (size_t)i1 * DC + q4);
            float4 v2 = *(const float4*)(zl + (size_t)i2 * DC + q4);
            float4 v3 = *(const float4*)(zl + (size_t)i3 * DC + q4);
            a0.x += v0.x*m0 + v1.x*m1 + v2.x*m2 + v3.x*m3;
            a0.y += v0.y*m0 + v1.y*m1 + v2.y*m2 + v3.y*m3;
            a0.z += v0.z*m0 + v1.z*m1 + v2.z*m2 + v3.z*m3;
            a0.w += v0.w*m0 + v1.w*m1 + v2.w*m2 + v3.w*m3;
        }
    }
    a0.x += __shfl_xor(a0.x, 2, 64);
    a0.y += __shfl_xor(a0.y, 2, 64);
    a0.z += __shfl_xor(a0.z, 2, 64);
    a0.w += __shfl_xor(a0.w, 2, 64);

    if (s == 0) {
        float inv = 1.0f / fmaxf((float)len, 1.0f);
        float4 r  = *(const float4*)(zr + (size_t)n * DC + q4);
        float4 bb = *(const float4*)(b2 + q4);
        float4 o;
        o.x = a0.x * inv + bb.x + r.x;
        o.y = a0.y * inv + bb.y + r.y;
        o.z = a0.z * inv + bb.z + r.z;
        o.w = a0.w * inv + bb.w + r.w;
        *(float4*)(out + (size_t)n * DC + q4) = o;
    }
}

extern "C" void kernel_launch(void* const* d_in, const int* in_sizes, int n_in,
                              void* d_out, int out_size, void* d_ws, size_t ws_size,
                              hipStream_t stream)
{
    const float* x   = (const float*)d_in[0];
    const int*   ei  = (const int*)d_in[1];
    const float* W1l = (const float*)d_in[2];
    const float* b1  = (const float*)d_in[3];
    const float* W1r = (const float*)d_in[4];
    const float* W2l = (const float*)d_in[5];
    const float* b2  = (const float*)d_in[6];
    const float* W2r = (const float*)d_in[7];
    float* out = (float*)d_out;

    const int* src = ei;
    const int* dst = ei + NE;

    // ---- workspace layout (floats first, 16B-aligned) ----
    float* xl  = (float*)d_ws;                      // NN*16
    float* xr  = xl + (size_t)NN * DH;              // NN*16
    float* zl  = xr + (size_t)NN * DH;              // NN*8
    float* zr  = zl + (size_t)NN * DC;              // NN*8
    int* cnt4  = (int*)(zr + (size_t)NN * DC);      // NN*4 (one int4 per node)
    u16* ell   = (u16*)(cnt4 + (size_t)NN * NREP);  // NN*64 u16 = 6.4MB
    // total ~17 MB

    k_zero    <<<(NN + 255) / 256, 256, 0, stream>>>(cnt4);
    k_fillgemm<<<NBF + NBG, 256, 0, stream>>>(x, W1l, W1r, src, dst, xl, xr, cnt4, ell);
    k_l1      <<<(NN * 8 + 255) / 256, 256, 0, stream>>>(cnt4, ell, xl, xr, b1, W2l, W2r, zl, zr);
    k_l2      <<<(NN * 4 + 255) / 256, 256, 0, stream>>>(cnt4, ell, zl, zr, b2, out);
}

// Round 17
// 69.328 us; speedup vs baseline: 2.3798x; 1.0252x over previous
//
#include <hip/hip_runtime.h>

#define NN 50000
#define NE 600000
#define DI 128
#define DH 16
#define DC 8
#define CAP 64      // ELL capacity per node
#define NBKT 8      // dst-range buckets (one per XCD)
#define NPB 6250    // nodes per bucket (8*6250 = 50000)
#define EPB 512     // edges per partition block (2/thread)
#define NPART 1172  // ceil(NE/EPB)
#define SCAP 128    // per-(block,bucket) segment capacity (mean 64, sd 7.5 -> 8.5 sigma)
#define NB2 2048    // fill blocks in k_fill2 (256 per bucket)
#define NBG 782     // gemm blocks in k_fill2

typedef unsigned short u16;
typedef unsigned int u32;

// ---------------- K1: partition edges into 8 dst-range buckets (LDS append) + zero cnt ----------------
__global__ __launch_bounds__(256) void k_part(
    const int* __restrict__ src, const int* __restrict__ dst,
    u32* __restrict__ buck, int* __restrict__ pcnt, int* __restrict__ cnt)
{
    __shared__ u32 sb[NBKT * SCAP];   // 4KB
    __shared__ int scnt[NBKT];
    const int tid = threadIdx.x;
    int gt = blockIdx.x * 256 + tid;
    if (gt < NN) cnt[gt] = 0;                    // zeroed before k_fill2 (stream order)
    if (tid < NBKT) scnt[tid] = 0;
    __syncthreads();

    const int base = blockIdx.x * EPB;
#pragma unroll
    for (int k = 0; k < 2; ++k) {
        int e = base + k * 256 + tid;
        if (e < NE) {
            int s = src[e], d = dst[e];
            int b = d / NPB;                     // 0..7
            int p = atomicAdd(&scnt[b], 1);      // LDS atomic
            if (p < SCAP) sb[b * SCAP + p] = (u32)s | ((u32)d << 16);
        }
    }
    __syncthreads();

    // coalesced flush of valid slots; per-segment count
    for (int i = tid; i < NBKT * SCAP; i += 256) {
        int b = i >> 7, sl = i & (SCAP - 1);
        if (sl < min(scnt[b], SCAP))
            buck[((size_t)b * NPART + blockIdx.x) * SCAP + sl] = sb[i];
    }
    if (tid < NBKT)
        pcnt[tid * NPART + blockIdx.x] = min(scnt[tid], SCAP);
}

// ---------------- K2: XCD-affine ELL fill (bucket = blockIdx&7) || gemm1 ----------------
__global__ __launch_bounds__(256) void k_fill2(
    const float* __restrict__ x,
    const float* __restrict__ W1l,
    const float* __restrict__ W1r,
    const u32* __restrict__ buck, const int* __restrict__ pcnt,
    float* __restrict__ xl, float* __restrict__ xr,
    int* __restrict__ cnt, u16* __restrict__ ell)
{
    __shared__ float Wc[DI][32];   // gemm blocks only

    if (blockIdx.x < NB2) {
        // ---- fill: bucket b's cnt/ell region (800KB) touched ONLY by blocks ≡ b (mod 8) -> XCD-local L2 ----
        const int b = blockIdx.x & 7;
        const int grp = blockIdx.x >> 3;          // 0..255
        const int half = threadIdx.x >> 7;        // two 128-lane streams per block
        const int lane = threadIdx.x & 127;
        for (int seg = grp * 2 + half; seg < NPART; seg += 2 * (NB2 / 8)) {
            int c = pcnt[b * NPART + seg];
            if (lane < c) {
                u32 v = buck[((size_t)b * NPART + seg) * SCAP + lane];
                int s = (int)(v & 0xFFFFu);
                int d = (int)(v >> 16);           // unsigned shift
                int pos = atomicAdd(&cnt[d], 1);
                if (pos < CAP) ell[(size_t)d * CAP + pos] = (u16)s;
            }
        }
        return;
    }

    // ---- gemm1: 4 threads/node; thread c computes cols [c*8, c*8+8) ----
    for (int i = threadIdx.x; i < DI * DH; i += 256) {
        int k = i >> 4, j = i & 15;
        Wc[k][j]      = W1l[i];
        Wc[k][j + 16] = W1r[i];
    }
    __syncthreads();

    int t = (blockIdx.x - NB2) * 256 + threadIdx.x;
    if (t >= NN * 4) return;
    int n = t >> 2, c = t & 3;
    const int co = c * 8;

    float acc[8];
#pragma unroll
    for (int j = 0; j < 8; ++j) acc[j] = 0.f;

    const float4* xrow = (const float4*)(x + (size_t)n * DI);
#pragma unroll 4
    for (int k4 = 0; k4 < DI / 4; ++k4) {
        float4 xv = xrow[k4];
#pragma unroll
        for (int kk = 0; kk < 4; ++kk) {
            const float* wr = &Wc[k4 * 4 + kk][co];
            float4 w0 = *(const float4*)(wr);
            float4 w1 = *(const float4*)(wr + 4);
            float xs = (&xv.x)[kk];
            acc[0] += xs * w0.x; acc[1] += xs * w0.y;
            acc[2] += xs * w0.z; acc[3] += xs * w0.w;
            acc[4] += xs * w1.x; acc[5] += xs * w1.y;
            acc[6] += xs * w1.z; acc[7] += xs * w1.w;
        }
    }
    float* o = (c < 2) ? (xl + (size_t)n * DH + c * 8)
                       : (xr + (size_t)n * DH + (c - 2) * 8);
    *(float4*)(o)     = make_float4(acc[0], acc[1], acc[2], acc[3]);
    *(float4*)(o + 4) = make_float4(acc[4], acc[5], acc[6], acc[7]);
}

// ---------------- K3: agg1 + relu + layer-2 GEMM; 8 threads/node ----------------
// sub = t&7: s = sub>>2 (slot parity), q = sub&3 (feature quad)
__global__ __launch_bounds__(256) void k_l1(
    const int* __restrict__ cnt, const u16* __restrict__ ell,
    const float* __restrict__ xl, const float* __restrict__ xr,
    const float* __restrict__ b1,
    const float* __restrict__ W2l, const float* __restrict__ W2r,
    float* __restrict__ zl, float* __restrict__ zr)
{
    int t = blockIdx.x * 256 + threadIdx.x;
    if (t >= NN * 8) return;
    int n = t >> 3, sub = t & 7, s = sub >> 2, q = sub & 3;
    const int q4 = q * 4;

    int len = min(cnt[n], CAP);
    const u16* lst = ell + (size_t)n * CAP;

    float4 a0 = make_float4(0.f, 0.f, 0.f, 0.f);
    for (int j = 0; j < len; j += 8) {
        uint4 w = *(const uint4*)(lst + j);      // 16B covers slots j..j+7
        int i0 = (int)(s ? (w.x >> 16) : (w.x & 0xFFFFu));
        int i1 = (int)(s ? (w.y >> 16) : (w.y & 0xFFFFu));
        int i2 = (int)(s ? (w.z >> 16) : (w.z & 0xFFFFu));
        int i3 = (int)(s ? (w.w >> 16) : (w.w & 0xFFFFu));
        float m0 = (j + 0 + s < len) ? 1.f : 0.f;
        float m1 = (j + 2 + s < len) ? 1.f : 0.f;
        float m2 = (j + 4 + s < len) ? 1.f : 0.f;
        float m3 = (j + 6 + s < len) ? 1.f : 0.f;
        i0 = (j + 0 + s < len) ? i0 : 0;
        i1 = (j + 2 + s < len) ? i1 : 0;
        i2 = (j + 4 + s < len) ? i2 : 0;
        i3 = (j + 6 + s < len) ? i3 : 0;
        float4 v0 = *(const float4*)(xl + (size_t)i0 * DH + q4);
        float4 v1 = *(const float4*)(xl + (size_t)i1 * DH + q4);
        float4 v2 = *(const float4*)(xl + (size_t)i2 * DH + q4);
        float4 v3 = *(const float4*)(xl + (size_t)i3 * DH + q4);
        a0.x += v0.x*m0 + v1.x*m1 + v2.x*m2 + v3.x*m3;
        a0.y += v0.y*m0 + v1.y*m1 + v2.y*m2 + v3.y*m3;
        a0.z += v0.z*m0 + v1.z*m1 + v2.z*m2 + v3.z*m3;
        a0.w += v0.w*m0 + v1.w*m1 + v2.w*m2 + v3.w*m3;
    }
    a0.x += __shfl_xor(a0.x, 4, 64);
    a0.y += __shfl_xor(a0.y, 4, 64);
    a0.z += __shfl_xor(a0.z, 4, 64);
    a0.w += __shfl_xor(a0.w, 4, 64);

    float inv = 1.0f / fmaxf((float)len, 1.0f);
    float4 r  = *(const float4*)(xr + (size_t)n * DH + q4);
    float4 bb = *(const float4*)(b1 + q4);
    float4 hq;
    hq.x = fmaxf(a0.x * inv + bb.x + r.x, 0.f);
    hq.y = fmaxf(a0.y * inv + bb.y + r.y, 0.f);
    hq.z = fmaxf(a0.z * inv + bb.z + r.z, 0.f);
    hq.w = fmaxf(a0.w * inv + bb.w + r.w, 0.f);

    float4 p1, p2, p3;
    p1.x = __shfl_xor(hq.x, 1, 64); p1.y = __shfl_xor(hq.y, 1, 64);
    p1.z = __shfl_xor(hq.z, 1, 64); p1.w = __shfl_xor(hq.w, 1, 64);
    p2.x = __shfl_xor(hq.x, 2, 64); p2.y = __shfl_xor(hq.y, 2, 64);
    p2.z = __shfl_xor(hq.z, 2, 64); p2.w = __shfl_xor(hq.w, 2, 64);
    p3.x = __shfl_xor(p1.x, 2, 64); p3.y = __shfl_xor(p1.y, 2, 64);
    p3.z = __shfl_xor(p1.z, 2, 64); p3.w = __shfl_xor(p1.w, 2, 64);
    float4 Q[4];
#pragma unroll
    for (int jq = 0; jq < 4; ++jq) {
        int d = jq ^ q;
        Q[jq] = (d == 0) ? hq : (d == 1) ? p1 : (d == 2) ? p2 : p3;
    }

    const float* Wbase = (q < 2) ? (W2l + q * 4) : (W2r + (q - 2) * 4);
    float4 acc = make_float4(0.f, 0.f, 0.f, 0.f);
#pragma unroll
    for (int k = 0; k < DH; ++k) {
        float hk = (k < 4) ? ((const float*)&Q[0])[k & 3]
                 : (k < 8) ? ((const float*)&Q[1])[k & 3]
                 : (k < 12) ? ((const float*)&Q[2])[k & 3]
                 : ((const float*)&Q[3])[k & 3];
        float4 wv = *(const float4*)(Wbase + k * 8);
        acc.x += hk * wv.x; acc.y += hk * wv.y;
        acc.z += hk * wv.z; acc.w += hk * wv.w;
    }
    if (s == 0) {
        float* dstp = (q < 2) ? (zl + (size_t)n * DC + q * 4)
                              : (zr + (size_t)n * DC + (q - 2) * 4);
        *(float4*)dstp = acc;
    }
}

// ---------------- K4: agg2 + b2 + zr -> out; 4 threads/node ----------------
// sub = t&3: s = sub>>1 (slot parity), q = sub&1 (feature quad)
__global__ __launch_bounds__(256) void k_l2(
    const int* __restrict__ cnt, const u16* __restrict__ ell,
    const float* __restrict__ zl, const float* __restrict__ zr,
    const float* __restrict__ b2, float* __restrict__ out)
{
    int t = blockIdx.x * 256 + threadIdx.x;
    if (t >= NN * 4) return;
    int n = t >> 2, sub = t & 3, s = sub >> 1, q = sub & 1;
    const int q4 = q * 4;
    int len = min(cnt[n], CAP);
    const u16* lst = ell + (size_t)n * CAP;

    float4 a0 = make_float4(0.f, 0.f, 0.f, 0.f);
    for (int j = 0; j < len; j += 8) {
        uint4 w = *(const uint4*)(lst + j);
        int i0 = (int)(s ? (w.x >> 16) : (w.x & 0xFFFFu));
        int i1 = (int)(s ? (w.y >> 16) : (w.y & 0xFFFFu));
        int i2 = (int)(s ? (w.z >> 16) : (w.z & 0xFFFFu));
        int i3 = (int)(s ? (w.w >> 16) : (w.w & 0xFFFFu));
        float m0 = (j + 0 + s < len) ? 1.f : 0.f;
        float m1 = (j + 2 + s < len) ? 1.f : 0.f;
        float m2 = (j + 4 + s < len) ? 1.f : 0.f;
        float m3 = (j + 6 + s < len) ? 1.f : 0.f;
        i0 = (j + 0 + s < len) ? i0 : 0;
        i1 = (j + 2 + s < len) ? i1 : 0;
        i2 = (j + 4 + s < len) ? i2 : 0;
        i3 = (j + 6 + s < len) ? i3 : 0;
        float4 v0 = *(const float4*)(zl + (size_t)i0 * DC + q4);
        float4 v1 = *(const float4*)(zl + (size_t)i1 * DC + q4);
        float4 v2 = *(const float4*)(zl + (size_t)i2 * DC + q4);
        float4 v3 = *(const float4*)(zl + (size_t)i3 * DC + q4);
        a0.x += v0.x*m0 + v1.x*m1 + v2.x*m2 + v3.x*m3;
        a0.y += v0.y*m0 + v1.y*m1 + v2.y*m2 + v3.y*m3;
        a0.z += v0.z*m0 + v1.z*m1 + v2.z*m2 + v3.z*m3;
        a0.w += v0.w*m0 + v1.w*m1 + v2.w*m2 + v3.w*m3;
    }
    a0.x += __shfl_xor(a0.x, 2, 64);
    a0.y += __shfl_xor(a0.y, 2, 64);
    a0.z += __shfl_xor(a0.z, 2, 64);
    a0.w += __shfl_xor(a0.w, 2, 64);

    if (s == 0) {
        float inv = 1.0f / fmaxf((float)len, 1.0f);
        float4 r  = *(const float4*)(zr + (size_t)n * DC + q4);
        float4 bb = *(const float4*)(b2 + q4);
        float4 o;
        o.x = a0.x * inv + bb.x + r.x;
        o.y = a0.y * inv + bb.y + r.y;
        o.z = a0.z * inv + bb.z + r.z;
        o.w = a0.w * inv + bb.w + r.w;
        *(float4*)(out + (size_t)n * DC + q4) = o;
    }
}

extern "C" void kernel_launch(void* const* d_in, const int* in_sizes, int n_in,
                              void* d_out, int out_size, void* d_ws, size_t ws_size,
                              hipStream_t stream)
{
    const float* x   = (const float*)d_in[0];
    const int*   ei  = (const int*)d_in[1];
    const float* W1l = (const float*)d_in[2];
    const float* b1  = (const float*)d_in[3];
    const float* W1r = (const float*)d_in[4];
    const float* W2l = (const float*)d_in[5];
    const float* b2  = (const float*)d_in[6];
    const float* W2r = (const float*)d_in[7];
    float* out = (float*)d_out;

    const int* src = ei;
    const int* dst = ei + NE;

    // ---- workspace layout (floats first, 16B-aligned) ----
    float* xl  = (float*)d_ws;                      // NN*16
    float* xr  = xl + (size_t)NN * DH;              // NN*16
    float* zl  = xr + (size_t)NN * DH;              // NN*8
    float* zr  = zl + (size_t)NN * DC;              // NN*8
    int* cnt   = (int*)(zr + (size_t)NN * DC);      // NN
    int* pcnt  = cnt + NN;                          // 8*NPART
    u16* ell   = (u16*)(pcnt + NBKT * NPART);       // NN*64 u16 = 6.4MB
    u32* buck  = (u32*)(ell + (size_t)NN * CAP);    // 8*NPART*SCAP u32 = 4.8MB
    // total ~21.2 MB

    k_part <<<NPART, 256, 0, stream>>>(src, dst, buck, pcnt, cnt);
    k_fill2<<<NB2 + NBG, 256, 0, stream>>>(x, W1l, W1r, buck, pcnt, xl, xr, cnt, ell);
    k_l1   <<<(NN * 8 + 255) / 256, 256, 0, stream>>>(cnt, ell, xl, xr, b1, W2l, W2r, zl, zr);
    k_l2   <<<(NN * 4 + 255) / 256, 256, 0, stream>>>(cnt, ell, zl, zr, b2, out);
}

// Round 18
// 52.463 us; speedup vs baseline: 3.1449x; 1.3215x over previous
//
#include <hip/hip_runtime.h>

#define NN 50000
#define NE 600000
#define DI 128
#define DH 16
#define DC 8
#define CAP 48      // ELL capacity; Poisson(12), P(>48) ~ 1e-18
#define NBKT 256    // dst-range buckets
#define NPB 196     // nodes per bucket (256*196 = 50176 >= NN)
#define EPB 512     // edges per partition block
#define NPART 1172  // ceil(NE/EPB)
#define SCAP 16     // slots per (block,bucket) segment; Poisson(2), P(>16) ~ 1e-11
#define NBG 782     // gemm blocks

typedef unsigned short u16;
typedef unsigned int u32;

// ---------------- K1: partition edges into 256 dst-range buckets; all I/O coalesced ----------------
__global__ __launch_bounds__(256) void k_part(
    const int* __restrict__ src, const int* __restrict__ dst,
    u32* __restrict__ buck, int* __restrict__ pcnt)
{
    __shared__ u32 sb[NBKT * SCAP];   // 16KB
    __shared__ int scnt[NBKT];
    const int tid = threadIdx.x;
    scnt[tid] = 0;                    // blockDim == NBKT == 256
    __syncthreads();

    const int base = blockIdx.x * EPB;
#pragma unroll
    for (int k = 0; k < 2; ++k) {
        int e = base + k * 256 + tid;
        if (e < NE) {
            int s = src[e], d = dst[e];
            int b = d / NPB;                     // 0..255
            int p = atomicAdd(&scnt[b], 1);      // LDS atomic
            if (p < SCAP) sb[b * SCAP + p] = (u32)s | ((u32)d << 16);
        }
    }
    __syncthreads();

    // flush: block-private contiguous 16KB chunk -> fully coalesced
    const size_t chunk = (size_t)blockIdx.x * NBKT * SCAP;
    for (int i = tid; i < NBKT * SCAP; i += 256) {
        int b = i >> 4, sl = i & (SCAP - 1);
        if (sl < min(scnt[b], SCAP)) buck[chunk + i] = sb[i];
    }
    pcnt[blockIdx.x * NBKT + tid] = min(scnt[tid], SCAP);  // coalesced row
}

// ---------------- K2: LDS ELL build per bucket (blocks 0..255) || gemm1 (blocks 256+) ----------------
__global__ __launch_bounds__(256) void k_fillgemm(
    const float* __restrict__ x,
    const float* __restrict__ W1l,
    const float* __restrict__ W1r,
    const u32* __restrict__ buck, const int* __restrict__ pcnt,
    float* __restrict__ xl, float* __restrict__ xr,
    int* __restrict__ cnt, u16* __restrict__ ell)
{
    const int tid = threadIdx.x;

    if (blockIdx.x < NBKT) {
        // ---- build bucket b's ELL rows in LDS; no global atomics, coalesced flush ----
        __shared__ u16 sell[NPB * CAP];   // 18.4KB
        __shared__ int scnt2[NPB];
        const int b = blockIdx.x;
        const int nbase = b * NPB;
        for (int i = tid; i < NPB; i += 256) scnt2[i] = 0;
        __syncthreads();

        for (int seg = tid; seg < NPART; seg += 256) {
            int c = pcnt[(size_t)seg * NBKT + b];
            const u32* p = buck + ((size_t)seg * NBKT + b) * SCAP;
            for (int k = 0; k < c; ++k) {
                u32 v = p[k];
                int ld = (int)(v >> 16) - nbase;     // unsigned shift; local node
                int q = atomicAdd(&scnt2[ld], 1);    // LDS atomic
                if (q < CAP) sell[ld * CAP + q] = (u16)(v & 0xFFFFu);
            }
        }
        __syncthreads();

        // flush rows (48 u16 = 6 uint4 per node), coalesced; garbage slots masked by len later
        for (int i = tid; i < NPB * 6; i += 256) {
            int node = i / 6, part = i - node * 6;
            int gn = nbase + node;
            if (gn < NN)
                ((uint4*)(ell + (size_t)gn * CAP))[part] = ((const uint4*)(sell + node * CAP))[part];
        }
        for (int i = tid; i < NPB; i += 256)
            if (nbase + i < NN) cnt[nbase + i] = min(scnt2[i], CAP);
        return;
    }

    // ---- gemm1: 4 threads/node; thread c computes cols [c*8, c*8+8) ----
    __shared__ float Wc[DI][32];
    for (int i = tid; i < DI * DH; i += 256) {
        int k = i >> 4, j = i & 15;
        Wc[k][j]      = W1l[i];
        Wc[k][j + 16] = W1r[i];
    }
    __syncthreads();

    int t = (blockIdx.x - NBKT) * 256 + tid;
    if (t >= NN * 4) return;
    int n = t >> 2, c = t & 3;
    const int co = c * 8;

    float acc[8];
#pragma unroll
    for (int j = 0; j < 8; ++j) acc[j] = 0.f;

    const float4* xrow = (const float4*)(x + (size_t)n * DI);
#pragma unroll 4
    for (int k4 = 0; k4 < DI / 4; ++k4) {
        float4 xv = xrow[k4];
#pragma unroll
        for (int kk = 0; kk < 4; ++kk) {
            const float* wr = &Wc[k4 * 4 + kk][co];
            float4 w0 = *(const float4*)(wr);
            float4 w1 = *(const float4*)(wr + 4);
            float xs = (&xv.x)[kk];
            acc[0] += xs * w0.x; acc[1] += xs * w0.y;
            acc[2] += xs * w0.z; acc[3] += xs * w0.w;
            acc[4] += xs * w1.x; acc[5] += xs * w1.y;
            acc[6] += xs * w1.z; acc[7] += xs * w1.w;
        }
    }
    float* o = (c < 2) ? (xl + (size_t)n * DH + c * 8)
                       : (xr + (size_t)n * DH + (c - 2) * 8);
    *(float4*)(o)     = make_float4(acc[0], acc[1], acc[2], acc[3]);
    *(float4*)(o + 4) = make_float4(acc[4], acc[5], acc[6], acc[7]);
}

// ---------------- K3: agg1 + relu + layer-2 GEMM; 8 threads/node ----------------
// sub = t&7: s = sub>>2 (slot parity), q = sub&3 (feature quad)
__global__ __launch_bounds__(256) void k_l1(
    const int* __restrict__ cnt, const u16* __restrict__ ell,
    const float* __restrict__ xl, const float* __restrict__ xr,
    const float* __restrict__ b1,
    const float* __restrict__ W2l, const float* __restrict__ W2r,
    float* __restrict__ zl, float* __restrict__ zr)
{
    int t = blockIdx.x * 256 + threadIdx.x;
    if (t >= NN * 8) return;
    int n = t >> 3, sub = t & 7, s = sub >> 2, q = sub & 3;
    const int q4 = q * 4;

    int len = min(cnt[n], CAP);
    const u16* lst = ell + (size_t)n * CAP;

    float4 a0 = make_float4(0.f, 0.f, 0.f, 0.f);
    for (int j = 0; j < len; j += 8) {
        uint4 w = *(const uint4*)(lst + j);      // 16B covers slots j..j+7
        int i0 = (int)(s ? (w.x >> 16) : (w.x & 0xFFFFu));
        int i1 = (int)(s ? (w.y >> 16) : (w.y & 0xFFFFu));
        int i2 = (int)(s ? (w.z >> 16) : (w.z & 0xFFFFu));
        int i3 = (int)(s ? (w.w >> 16) : (w.w & 0xFFFFu));
        float m0 = (j + 0 + s < len) ? 1.f : 0.f;
        float m1 = (j + 2 + s < len) ? 1.f : 0.f;
        float m2 = (j + 4 + s < len) ? 1.f : 0.f;
        float m3 = (j + 6 + s < len) ? 1.f : 0.f;
        i0 = (j + 0 + s < len) ? i0 : 0;
        i1 = (j + 2 + s < len) ? i1 : 0;
        i2 = (j + 4 + s < len) ? i2 : 0;
        i3 = (j + 6 + s < len) ? i3 : 0;
        float4 v0 = *(const float4*)(xl + (size_t)i0 * DH + q4);
        float4 v1 = *(const float4*)(xl + (size_t)i1 * DH + q4);
        float4 v2 = *(const float4*)(xl + (size_t)i2 * DH + q4);
        float4 v3 = *(const float4*)(xl + (size_t)i3 * DH + q4);
        a0.x += v0.x*m0 + v1.x*m1 + v2.x*m2 + v3.x*m3;
        a0.y += v0.y*m0 + v1.y*m1 + v2.y*m2 + v3.y*m3;
        a0.z += v0.z*m0 + v1.z*m1 + v2.z*m2 + v3.z*m3;
        a0.w += v0.w*m0 + v1.w*m1 + v2.w*m2 + v3.w*m3;
    }
    a0.x += __shfl_xor(a0.x, 4, 64);
    a0.y += __shfl_xor(a0.y, 4, 64);
    a0.z += __shfl_xor(a0.z, 4, 64);
    a0.w += __shfl_xor(a0.w, 4, 64);

    float inv = 1.0f / fmaxf((float)len, 1.0f);
    float4 r  = *(const float4*)(xr + (size_t)n * DH + q4);
    float4 bb = *(const float4*)(b1 + q4);
    float4 hq;
    hq.x = fmaxf(a0.x * inv + bb.x + r.x, 0.f);
    hq.y = fmaxf(a0.y * inv + bb.y + r.y, 0.f);
    hq.z = fmaxf(a0.z * inv + bb.z + r.z, 0.f);
    hq.w = fmaxf(a0.w * inv + bb.w + r.w, 0.f);

    float4 p1, p2, p3;
    p1.x = __shfl_xor(hq.x, 1, 64); p1.y = __shfl_xor(hq.y, 1, 64);
    p1.z = __shfl_xor(hq.z, 1, 64); p1.w = __shfl_xor(hq.w, 1, 64);
    p2.x = __shfl_xor(hq.x, 2, 64); p2.y = __shfl_xor(hq.y, 2, 64);
    p2.z = __shfl_xor(hq.z, 2, 64); p2.w = __shfl_xor(hq.w, 2, 64);
    p3.x = __shfl_xor(p1.x, 2, 64); p3.y = __shfl_xor(p1.y, 2, 64);
    p3.z = __shfl_xor(p1.z, 2, 64); p3.w = __shfl_xor(p1.w, 2, 64);
    float4 Q[4];
#pragma unroll
    for (int jq = 0; jq < 4; ++jq) {
        int d = jq ^ q;
        Q[jq] = (d == 0) ? hq : (d == 1) ? p1 : (d == 2) ? p2 : p3;
    }

    const float* Wbase = (q < 2) ? (W2l + q * 4) : (W2r + (q - 2) * 4);
    float4 acc = make_float4(0.f, 0.f, 0.f, 0.f);
#pragma unroll
    for (int k = 0; k < DH; ++k) {
        float hk = (k < 4) ? ((const float*)&Q[0])[k & 3]
                 : (k < 8) ? ((const float*)&Q[1])[k & 3]
                 : (k < 12) ? ((const float*)&Q[2])[k & 3]
                 : ((const float*)&Q[3])[k & 3];
        float4 wv = *(const float4*)(Wbase + k * 8);
        acc.x += hk * wv.x; acc.y += hk * wv.y;
        acc.z += hk * wv.z; acc.w += hk * wv.w;
    }
    if (s == 0) {
        float* dstp = (q < 2) ? (zl + (size_t)n * DC + q * 4)
                              : (zr + (size_t)n * DC + (q - 2) * 4);
        *(float4*)dstp = acc;
    }
}

// ---------------- K4: agg2 + b2 + zr -> out; 4 threads/node ----------------
// sub = t&3: s = sub>>1 (slot parity), q = sub&1 (feature quad)
__global__ __launch_bounds__(256) void k_l2(
    const int* __restrict__ cnt, const u16* __restrict__ ell,
    const float* __restrict__ zl, const float* __restrict__ zr,
    const float* __restrict__ b2, float* __restrict__ out)
{
    int t = blockIdx.x * 256 + threadIdx.x;
    if (t >= NN * 4) return;
    int n = t >> 2, sub = t & 3, s = sub >> 1, q = sub & 1;
    const int q4 = q * 4;
    int len = min(cnt[n], CAP);
    const u16* lst = ell + (size_t)n * CAP;

    float4 a0 = make_float4(0.f, 0.f, 0.f, 0.f);
    for (int j = 0; j < len; j += 8) {
        uint4 w = *(const uint4*)(lst + j);
        int i0 = (int)(s ? (w.x >> 16) : (w.x & 0xFFFFu));
        int i1 = (int)(s ? (w.y >> 16) : (w.y & 0xFFFFu));
        int i2 = (int)(s ? (w.z >> 16) : (w.z & 0xFFFFu));
        int i3 = (int)(s ? (w.w >> 16) : (w.w & 0xFFFFu));
        float m0 = (j + 0 + s < len) ? 1.f : 0.f;
        float m1 = (j + 2 + s < len) ? 1.f : 0.f;
        float m2 = (j + 4 + s < len) ? 1.f : 0.f;
        float m3 = (j + 6 + s < len) ? 1.f : 0.f;
        i0 = (j + 0 + s < len) ? i0 : 0;
        i1 = (j + 2 + s < len) ? i1 : 0;
        i2 = (j + 4 + s < len) ? i2 : 0;
        i3 = (j + 6 + s < len) ? i3 : 0;
        float4 v0 = *(const float4*)(zl + (size_t)i0 * DC + q4);
        float4 v1 = *(const float4*)(zl + (size_t)i1 * DC + q4);
        float4 v2 = *(const float4*)(zl + (size_t)i2 * DC + q4);
        float4 v3 = *(const float4*)(zl + (size_t)i3 * DC + q4);
        a0.x += v0.x*m0 + v1.x*m1 + v2.x*m2 + v3.x*m3;
        a0.y += v0.y*m0 + v1.y*m1 + v2.y*m2 + v3.y*m3;
        a0.z += v0.z*m0 + v1.z*m1 + v2.z*m2 + v3.z*m3;
        a0.w += v0.w*m0 + v1.w*m1 + v2.w*m2 + v3.w*m3;
    }
    a0.x += __shfl_xor(a0.x, 2, 64);
    a0.y += __shfl_xor(a0.y, 2, 64);
    a0.z += __shfl_xor(a0.z, 2, 64);
    a0.w += __shfl_xor(a0.w, 2, 64);

    if (s == 0) {
        float inv = 1.0f / fmaxf((float)len, 1.0f);
        float4 r  = *(const float4*)(zr + (size_t)n * DC + q4);
        float4 bb = *(const float4*)(b2 + q4);
        float4 o;
        o.x = a0.x * inv + bb.x + r.x;
        o.y = a0.y * inv + bb.y + r.y;
        o.z = a0.z * inv + bb.z + r.z;
        o.w = a0.w * inv + bb.w + r.w;
        *(float4*)(out + (size_t)n * DC + q4) = o;
    }
}

extern "C" void kernel_launch(void* const* d_in, const int* in_sizes, int n_in,
                              void* d_out, int out_size, void* d_ws, size_t ws_size,
                              hipStream_t stream)
{
    const float* x   = (const float*)d_in[0];
    const int*   ei  = (const int*)d_in[1];
    const float* W1l = (const float*)d_in[2];
    const float* b1  = (const float*)d_in[3];
    const float* W1r = (const float*)d_in[4];
    const float* W2l = (const float*)d_in[5];
    const float* b2  = (const float*)d_in[6];
    const float* W2r = (const float*)d_in[7];
    float* out = (float*)d_out;

    const int* src = ei;
    const int* dst = ei + NE;

    // ---- workspace layout ----
    float* xl  = (float*)d_ws;                        // NN*16
    float* xr  = xl + (size_t)NN * DH;                // NN*16
    float* zl  = xr + (size_t)NN * DH;                // NN*8
    float* zr  = zl + (size_t)NN * DC;                // NN*8
    u16* ell   = (u16*)(zr + (size_t)NN * DC);        // NN*48 u16 = 4.8MB (16B aligned)
    int* cnt   = (int*)(ell + (size_t)NN * CAP);      // NN
    int* pcnt  = cnt + NN;                            // NPART*NBKT = 1.2MB
    u32* buck  = (u32*)(pcnt + (size_t)NPART * NBKT); // NPART*NBKT*SCAP u32 = 19.2MB
    // total ~35 MB

    k_part    <<<NPART, 256, 0, stream>>>(src, dst, buck, pcnt);
    k_fillgemm<<<NBKT + NBG, 256, 0, stream>>>(x, W1l, W1r, buck, pcnt, xl, xr, cnt, ell);
    k_l1      <<<(NN * 8 + 255) / 256, 256, 0, stream>>>(cnt, ell, xl, xr, b1, W2l, W2r, zl, zr);
    k_l2      <<<(NN * 4 + 255) / 256, 256, 0, stream>>>(cnt, ell, zl, zr, b2, out);
}